// Round 7
// baseline (146.791 us; speedup 1.0000x reference)
//
#include <hip/hip_runtime.h>

// PointCloudCompletionLoss — Chamfer-L2, split-bf16 MFMA, block-complete mins.
// t(x,y) = -2 x.y + |y|^2 via ONE v_mfma_f32_32x32x16_bf16 per 32x32 tile
// (11 of 16 K-slots; x=xh+xl, y=yh+yl hi/lo splits, xl*yl dropped ~2^-17).
// Each block owns 512 X x FULL Y (Y looped in 1024-pt LDS chunks), so every
// X-min completes in-block: no global mins array, no sentinel memset, no
// atomics. Block reduces sum(d) to one float, plain-stored to d_ws; a
// 1-block kernel applies segment weights and writes out. 2 graph nodes.
//
// A-frags are PRE-BUILT in LDS at staging time (lo-half lanes / hi-half
// lanes as two uint4 arrays) -> inner loop = 1 ds_read_b128 + 4 MFMA +
// 32 v_min3 per 4096 pairs.
//
// Blocks (200): p0 [0,8): coarse->gt (b=W>>1, 2 X-chunks of 512)
//               p1 [8,72): gt->coarse   p2 [72,136): fine->gt
//               p3 [136,200): gt->fine  (b=l>>4, 16 X-chunks)
constexpr int NSTAGE = 200;

typedef __attribute__((ext_vector_type(8)))  short bf16x8;
typedef __attribute__((ext_vector_type(16))) float f32x16;

__device__ __forceinline__ void split2(float v, unsigned& h, unsigned& l) {
    const unsigned uh = __float_as_uint(v) & 0xFFFF0000u;
    h = uh >> 16;
    l = __float_as_uint(v - __uint_as_float(uh)) >> 16;
}

__global__ __launch_bounds__(256) void pccl_stage(
    const float* __restrict__ Xc, const float* __restrict__ Xf,
    const float* __restrict__ G, float* __restrict__ partials)
{
    __shared__ uint4 alo[1024];   // A-frag dwords, lanes<32 view
    __shared__ uint4 ahi[1024];   // A-frag dwords, lanes>=32 view
    __shared__ float psh[4];
    const int tid  = threadIdx.x;
    const int lane = tid & 63;
    const int wv   = __builtin_amdgcn_readfirstlane(tid >> 6);
    const int l31  = lane & 31;
    const bool hi  = lane >= 32;
    const int W    = blockIdx.x;

    const float* Xp; const float* Yp; int NX, NY, b, chunk;
    if (W < 8)        {              Xp=Xc; Yp=G;  NX=1024; NY=8192; b=W>>1; chunk=W&1; }
    else if (W < 72)  { int l=W-8;   Xp=G;  Yp=Xc; NX=8192; NY=1024; b=l>>4; chunk=l&15; }
    else if (W < 136) { int l=W-72;  Xp=Xf; Yp=G;  NX=8192; NY=8192; b=l>>4; chunk=l&15; }
    else              { int l=W-136; Xp=G;  Yp=Xf; NX=8192; NY=8192; b=l>>4; chunk=l&15; }

    // ---- B-frags: 4 frags x 32 X points per wave (wave owns 128 X) ----
    // B k-seq (x scaled -2): lanes<32 [m2xh0,m2xh0,m2xl0, m2xh1,m2xh1,m2xl1,
    // m2xh2,m2xh2]; lanes>=32 [m2xl2, 1, 1, 0...]. (verified round 6)
    const float* xg = Xp + ((size_t)b * NX + (size_t)chunk * 512 + (size_t)wv * 128) * 3;
    bf16x8 Bf[4]; float x2s[4];
    #pragma unroll
    for (int f = 0; f < 4; ++f) {
        const int p = f * 32 + l31;
        const float x0 = xg[p*3+0], x1 = xg[p*3+1], x2 = xg[p*3+2];
        x2s[f] = fmaf(x0, x0, fmaf(x1, x1, x2 * x2));
        unsigned sh0, sl0, sh1, sl1, sh2, sl2;
        split2(-2.f * x0, sh0, sl0);
        split2(-2.f * x1, sh1, sl1);
        split2(-2.f * x2, sh2, sl2);
        union { unsigned u[4]; bf16x8 v; } bu;
        bu.u[0] = hi ? (sl2 | (0x3F80u << 16)) : (sh0 | (sh0 << 16));
        bu.u[1] = hi ? 0x3F80u                 : (sl0 | (sh1 << 16));
        bu.u[2] = hi ? 0u                      : (sh1 | (sl1 << 16));
        bu.u[3] = hi ? 0u                      : (sh2 | (sh2 << 16));
        Bf[f] = bu.v;
    }

    float best[4][8];
    #pragma unroll
    for (int f = 0; f < 4; ++f)
        #pragma unroll
        for (int j = 0; j < 8; ++j) best[f][j] = 3.0e38f;

    const f32x16 zc = (f32x16)0.0f;
    const uint4* __restrict__ abase = hi ? ahi : alo;

    for (int c = 0; c < NY / 1024; ++c) {
        __syncthreads();   // previous chunk's readers done before overwrite
        // ---- stage 1024 Y as prebuilt A-frag dwords (4 Y per thread) ----
        // A k-seq: lanes<32 [yh0,yl0,yh0, yh1,yl1,yh1, yh2,yl2];
        //          lanes>=32 [yh2, wh, wl, 0...]   (w = |y|^2)
        const float* yg = Yp + ((size_t)b * NY + (size_t)c * 1024) * 3;
        #pragma unroll
        for (int it = 0; it < 4; ++it) {
            const int pt = tid + 256 * it;
            const float y0 = yg[pt*3+0], y1 = yg[pt*3+1], y2 = yg[pt*3+2];
            const float w  = fmaf(y0, y0, fmaf(y1, y1, y2 * y2));
            unsigned h0, L0, h1, L1, h2, L2, hw, Lw;
            split2(y0, h0, L0); split2(y1, h1, L1);
            split2(y2, h2, L2); split2(w,  hw, Lw);
            alo[pt] = make_uint4(h0 | (L0 << 16), h0 | (h1 << 16),
                                 L1 | (h1 << 16), h2 | (L2 << 16));
            ahi[pt] = make_uint4(h2 | (hw << 16), Lw, 0u, 0u);
        }
        __syncthreads();

        // ---- 32 Y-tiles: 1 ds_read_b128 + 4 MFMA + 32 min3 each ----
        #pragma unroll 4
        for (int t = 0; t < 32; ++t) {
            const uint4 dd = abase[t * 32 + l31];
            union { uint4 u; bf16x8 v; } au; au.u = dd;
            const bf16x8 Af = au.v;
            #pragma unroll
            for (int f = 0; f < 4; ++f) {
                const f32x16 acc = __builtin_amdgcn_mfma_f32_32x32x16_bf16(Af, Bf[f], zc, 0, 0, 0);
                #pragma unroll
                for (int j = 0; j < 8; ++j)
                    best[f][j] = fminf(fminf(best[f][j], acc[2*j]), acc[2*j+1]);
            }
        }
    }

    // ---- epilogue: per-X d = |x|^2 + min_t (>=0), sum all, one partial ----
    float s = 0.f;
    #pragma unroll
    for (int f = 0; f < 4; ++f) {
        const float m0 = fminf(fminf(best[f][0], best[f][1]), best[f][2]);
        const float m1 = fminf(fminf(best[f][3], best[f][4]), best[f][5]);
        const float m2 = fminf(fminf(best[f][6], best[f][7]), m0);
        float tm = fminf(m1, m2);
        tm = fminf(tm, __shfl_xor(tm, 32, 64));  // merge k-halves
        s += fmaxf(x2s[f] + tm, 0.0f);
    }
    // halves hold duplicate d's -> sum 64 lanes, x0.5
    #pragma unroll
    for (int off = 1; off < 64; off <<= 1) s += __shfl_xor(s, off, 64);
    if (lane == 0) psh[wv] = s * 0.5f;
    __syncthreads();
    if (tid == 0) partials[W] = psh[0] + psh[1] + psh[2] + psh[3];
}

__global__ __launch_bounds__(256) void pccl_sum(
    const float* __restrict__ partials,
    const int* __restrict__ pc, const int* __restrict__ pf,
    float* __restrict__ out)
{
    const int tid = threadIdx.x;
    const int lane = tid & 63;
    const int wv = tid >> 6;
    float v = (tid < NSTAGE) ? partials[tid] : 0.f;
    float w0 = (tid < 8) ? v * (1.f/4096.f) : ((tid < 72) ? v * (1.f/32768.f) : 0.f);
    float w1 = (tid >= 72) ? v * (1.f/32768.f) : 0.f;
    #pragma unroll
    for (int off = 1; off < 64; off <<= 1) {
        w0 += __shfl_xor(w0, off, 64);
        w1 += __shfl_xor(w1, off, 64);
    }
    __shared__ float s0[4], s1[4];
    if (lane == 0) { s0[wv] = w0; s1[wv] = w1; }
    __syncthreads();
    if (tid == 0) {
        out[0] = (s0[0] + s0[1] + s0[2] + s0[3]) * (float)pc[0];
        out[1] = (s1[0] + s1[1] + s1[2] + s1[3]) * (float)pf[0];
    }
}

extern "C" void kernel_launch(void* const* d_in, const int* in_sizes, int n_in,
                              void* d_out, int out_size, void* d_ws, size_t ws_size,
                              hipStream_t stream) {
    const float* coarse = (const float*)d_in[0];
    const float* fine   = (const float*)d_in[1];
    const float* gt     = (const float*)d_in[2];
    const int*   pc     = (const int*)d_in[3];
    const int*   pf     = (const int*)d_in[4];
    float* out = (float*)d_out;
    float* partials = (float*)d_ws;   // 200 floats, fully written before read

    pccl_stage<<<NSTAGE, 256, 0, stream>>>(coarse, fine, gt, partials);
    pccl_sum<<<1, 256, 0, stream>>>(partials, pc, pf, out);
}

// Round 8
// 96.082 us; speedup vs baseline: 1.5278x; 1.5278x over previous
//
#include <hip/hip_runtime.h>

// PointCloudCompletionLoss — Chamfer-L2, split-bf16 MFMA, Y-split grid.
// t(x,y) = -2 x.y + |y|^2 via ONE v_mfma_f32_32x32x16_bf16 per 32x32 tile
// (11 of 16 K-slots; x=xh+xl, y=yh+yl hi/lo splits, xl*yl dropped ~2^-17).
// Grid: 1152 blocks (4.5 waves/SIMD — round 7 showed <2 waves/SIMD is
// latency-death). Block = 512 X x 1024 Y (one split); A-frags PRE-BUILT in
// LDS at staging (round 7's win): inner loop = 1 ds_read_b128 (offset imm)
// + 4 MFMA + 32 v_min3 per 4096 pairs. Cross-split combine: uint-bit
// atomicMin into sentinel-memset mins (d >= 0). Sum: single 1024-thread
// block, plain store (no out-memset). 3 graph nodes.
constexpr int NMINS = 102400;   // 4096 + 3*32768 directed mins
constexpr int NBLK  = 1152;

typedef __attribute__((ext_vector_type(8)))  short bf16x8;
typedef __attribute__((ext_vector_type(16))) float f32x16;

__device__ __forceinline__ void split2(float v, unsigned& h, unsigned& l) {
    const unsigned uh = __float_as_uint(v) & 0xFFFF0000u;
    h = uh >> 16;
    l = __float_as_uint(v - __uint_as_float(uh)) >> 16;
}

// Pass table (block W):
//  p0 [  0, 64): coarse->gt  NX=1024 NY=8192 splits 8  chunks  2  mbase 0
//  p1 [ 64,128): gt->coarse  NX=8192 NY=1024 splits 1  chunks 16  mbase 4096
//  p2 [128,640): fine->gt    NX=8192 NY=8192 splits 8  chunks 16  mbase 36864
//  p3 [640,1152): gt->fine   NX=8192 NY=8192 splits 8  chunks 16  mbase 69632

__global__ __launch_bounds__(256) void pccl_stage(
    const float* __restrict__ Xc, const float* __restrict__ Xf,
    const float* __restrict__ G, unsigned* __restrict__ mins)
{
    __shared__ uint4 alo[1024];   // prebuilt A-frag dwords, lanes<32 view
    __shared__ uint4 ahi[1024];   // prebuilt A-frag dwords, lanes>=32 view
    const int tid  = threadIdx.x;
    const int lane = tid & 63;
    const int wv   = __builtin_amdgcn_readfirstlane(tid >> 6);
    const int l31  = lane & 31;
    const bool hi  = lane >= 32;
    const int W    = blockIdx.x;

    const float* Xp; const float* Yp;
    int NX, NY, ls, lc, local, mbase;
    if (W < 64)        { Xp=Xc; Yp=G;  NX=1024; NY=8192; ls=3; lc=1; local=W;     mbase=0; }
    else if (W < 128)  { Xp=G;  Yp=Xc; NX=8192; NY=1024; ls=0; lc=4; local=W-64;  mbase=4096; }
    else if (W < 640)  { Xp=Xf; Yp=G;  NX=8192; NY=8192; ls=3; lc=4; local=W-128; mbase=36864; }
    else               { Xp=G;  Yp=Xf; NX=8192; NY=8192; ls=3; lc=4; local=W-640; mbase=69632; }
    const int split  = local & ((1 << ls) - 1);
    const int rest   = local >> ls;
    const int chunk4 = rest & ((1 << lc) - 1);
    const int b      = rest >> lc;

    // ---- stage 1024 Y as prebuilt A-frag dwords (4 Y per thread) ----
    // A k-seq: lanes<32 [yh0,yl0,yh0, yh1,yl1,yh1, yh2,yl2];
    //          lanes>=32 [yh2, wh, wl, 0...]  (w = |y|^2)   (verified r6/r7)
    const float* yg = Yp + ((size_t)b * NY + (size_t)split * 1024) * 3;
    #pragma unroll
    for (int it = 0; it < 4; ++it) {
        const int pt = tid + 256 * it;
        const float y0 = yg[pt*3+0], y1 = yg[pt*3+1], y2 = yg[pt*3+2];
        const float w  = fmaf(y0, y0, fmaf(y1, y1, y2 * y2));
        unsigned h0, L0, h1, L1, h2, L2, hw, Lw;
        split2(y0, h0, L0); split2(y1, h1, L1);
        split2(y2, h2, L2); split2(w,  hw, Lw);
        alo[pt] = make_uint4(h0 | (L0 << 16), h0 | (h1 << 16),
                             L1 | (h1 << 16), h2 | (L2 << 16));
        ahi[pt] = make_uint4(h2 | (hw << 16), Lw, 0u, 0u);
    }

    // ---- B-frags: 4 frags x 32 X points per wave (wave owns 128 X) ----
    // B k-seq (x scaled -2): lanes<32 [m2xh0,m2xh0,m2xl0, m2xh1,m2xh1,m2xl1,
    // m2xh2,m2xh2]; lanes>=32 [m2xl2, 1, 1, 0...]   (verified r6)
    const float* xg = Xp + ((size_t)b * NX + (size_t)chunk4 * 512 + (size_t)wv * 128) * 3;
    bf16x8 Bf[4]; float x2s[4];
    #pragma unroll
    for (int f = 0; f < 4; ++f) {
        const int p = f * 32 + l31;
        const float x0 = xg[p*3+0], x1 = xg[p*3+1], x2 = xg[p*3+2];
        x2s[f] = fmaf(x0, x0, fmaf(x1, x1, x2 * x2));
        unsigned sh0, sl0, sh1, sl1, sh2, sl2;
        split2(-2.f * x0, sh0, sl0);
        split2(-2.f * x1, sh1, sl1);
        split2(-2.f * x2, sh2, sl2);
        union { unsigned u[4]; bf16x8 v; } bu;
        bu.u[0] = hi ? (sl2 | (0x3F80u << 16)) : (sh0 | (sh0 << 16));
        bu.u[1] = hi ? 0x3F80u                 : (sl0 | (sh1 << 16));
        bu.u[2] = hi ? 0u                      : (sh1 | (sl1 << 16));
        bu.u[3] = hi ? 0u                      : (sh2 | (sh2 << 16));
        Bf[f] = bu.v;
    }

    float best[4][8];
    #pragma unroll
    for (int f = 0; f < 4; ++f)
        #pragma unroll
        for (int j = 0; j < 8; ++j) best[f][j] = 3.0e38f;

    const f32x16 zc = (f32x16)0.0f;
    const uint4* __restrict__ abase = hi ? ahi : alo;

    __syncthreads();

    // ---- 32 Y-tiles: 1 ds_read_b128 (offset imm) + 4 MFMA + 32 min3 ----
    #pragma unroll 4
    for (int t = 0; t < 32; ++t) {
        const uint4 dd = abase[t * 32 + l31];
        union { uint4 u; bf16x8 v; } au; au.u = dd;
        const bf16x8 Af = au.v;
        #pragma unroll
        for (int f = 0; f < 4; ++f) {
            const f32x16 acc = __builtin_amdgcn_mfma_f32_32x32x16_bf16(Af, Bf[f], zc, 0, 0, 0);
            #pragma unroll
            for (int j = 0; j < 8; ++j)
                best[f][j] = fminf(fminf(best[f][j], acc[2*j]), acc[2*j+1]);
        }
    }

    // ---- epilogue: fold 8 best, merge k-halves, d = |x|^2 + tmin >= 0 ----
    unsigned* mp = mins + mbase + b * NX + chunk4 * 512 + wv * 128;
    #pragma unroll
    for (int f = 0; f < 4; ++f) {
        const float m0 = fminf(fminf(best[f][0], best[f][1]), best[f][2]);
        const float m1 = fminf(fminf(best[f][3], best[f][4]), best[f][5]);
        const float m2 = fminf(fminf(best[f][6], best[f][7]), m0);
        float tm = fminf(m1, m2);
        tm = fminf(tm, __shfl_xor(tm, 32, 64));
        const float d = fmaxf(x2s[f] + tm, 0.0f);
        atomicMin(mp + f * 32 + l31, __float_as_uint(d));
    }
}

// ONE block, 1024 threads: read 400 KB of mins, weighted sum, plain store.
__global__ __launch_bounds__(1024) void pccl_sum(
    const unsigned* __restrict__ mins,
    const int* __restrict__ pc, const int* __restrict__ pf,
    float* __restrict__ out)
{
    const int tid = threadIdx.x;
    const int lane = tid & 63;
    const int wv = tid >> 6;
    float w0 = 0.f, w1 = 0.f;   // coarse-loss sum, fine-loss sum (unscaled)
    // uint4 q covers elements 4q..4q+3; segment boundaries (1024/9216/17408
    // in uint4 units) are uint4-aligned.
    #pragma unroll 5
    for (int k = 0; k < 25; ++k) {
        const int q = tid + 1024 * k;
        const uint4 v = ((const uint4*)mins)[q];
        const float s = __uint_as_float(v.x) + __uint_as_float(v.y)
                      + __uint_as_float(v.z) + __uint_as_float(v.w);
        if (q < 1024)       w0 += s * (1.f / 4096.f);
        else if (q < 9216)  w0 += s * (1.f / 32768.f);
        else                w1 += s * (1.f / 32768.f);
    }
    #pragma unroll
    for (int off = 1; off < 64; off <<= 1) {
        w0 += __shfl_xor(w0, off, 64);
        w1 += __shfl_xor(w1, off, 64);
    }
    __shared__ float s0[16], s1[16];
    if (lane == 0) { s0[wv] = w0; s1[wv] = w1; }
    __syncthreads();
    if (tid == 0) {
        float a0 = 0.f, a1 = 0.f;
        #pragma unroll
        for (int i = 0; i < 16; ++i) { a0 += s0[i]; a1 += s1[i]; }
        out[0] = a0 * (float)pc[0];
        out[1] = a1 * (float)pf[0];
    }
}

extern "C" void kernel_launch(void* const* d_in, const int* in_sizes, int n_in,
                              void* d_out, int out_size, void* d_ws, size_t ws_size,
                              hipStream_t stream) {
    const float* coarse = (const float*)d_in[0];
    const float* fine   = (const float*)d_in[1];
    const float* gt     = (const float*)d_in[2];
    const int*   pc     = (const int*)d_in[3];
    const int*   pf     = (const int*)d_in[4];
    float* out = (float*)d_out;
    unsigned* mins = (unsigned*)d_ws;

    hipMemsetAsync(mins, 0x7F, (size_t)NMINS * 4, stream);  // 3.396e38 sentinel
    pccl_stage<<<NBLK, 256, 0, stream>>>(coarse, fine, gt, mins);
    pccl_sum<<<1, 1024, 0, stream>>>(mins, pc, pf, out);
}

// Round 9
// 86.007 us; speedup vs baseline: 1.7067x; 1.1171x over previous
//
#include <hip/hip_runtime.h>

// PointCloudCompletionLoss — Chamfer-L2, split-bf16 MFMA, Y-split grid.
// t(x,y) = -2 x.y + |y|^2 via ONE v_mfma_f32_32x32x16_bf16 per 32x32 tile
// (11 of 16 K-slots; x=xh+xl, y=yh+yl hi/lo splits, xl*yl dropped ~2^-17).
// Grid: 1152 blocks (~4.5 waves/SIMD). Block = 512 X x 1024 Y; A-frags
// PRE-BUILT in LDS at staging; inner loop = 1 ds_read_b128 + 4 MFMA +
// 32 v_min3 per 4096 pairs. R9 change vs R8: __launch_bounds__(256,4)
// (VGPR cap 128, was 60) + explicit 2-wide MFMA pipelining so accs stay
// in VGPRs and a second MFMA issues during the first's min-folds.
// Cross-split combine: uint-bit atomicMin into sentinel-memset mins
// (d >= 0). Sum: one 1024-thread block, plain store. 3 graph nodes.
constexpr int NMINS = 102400;   // 4096 + 3*32768 directed mins
constexpr int NBLK  = 1152;

typedef __attribute__((ext_vector_type(8)))  short bf16x8;
typedef __attribute__((ext_vector_type(16))) float f32x16;

__device__ __forceinline__ void split2(float v, unsigned& h, unsigned& l) {
    const unsigned uh = __float_as_uint(v) & 0xFFFF0000u;
    h = uh >> 16;
    l = __float_as_uint(v - __uint_as_float(uh)) >> 16;
}

// Pass table (block W):
//  p0 [  0, 64): coarse->gt  NX=1024 NY=8192 splits 8  chunks  2  mbase 0
//  p1 [ 64,128): gt->coarse  NX=8192 NY=1024 splits 1  chunks 16  mbase 4096
//  p2 [128,640): fine->gt    NX=8192 NY=8192 splits 8  chunks 16  mbase 36864
//  p3 [640,1152): gt->fine   NX=8192 NY=8192 splits 8  chunks 16  mbase 69632

__global__ __launch_bounds__(256, 4) void pccl_stage(
    const float* __restrict__ Xc, const float* __restrict__ Xf,
    const float* __restrict__ G, unsigned* __restrict__ mins)
{
    __shared__ uint4 alo[1024];   // prebuilt A-frag dwords, lanes<32 view
    __shared__ uint4 ahi[1024];   // prebuilt A-frag dwords, lanes>=32 view
    const int tid  = threadIdx.x;
    const int lane = tid & 63;
    const int wv   = __builtin_amdgcn_readfirstlane(tid >> 6);
    const int l31  = lane & 31;
    const bool hi  = lane >= 32;
    const int W    = blockIdx.x;

    const float* Xp; const float* Yp;
    int NX, NY, ls, lc, local, mbase;
    if (W < 64)        { Xp=Xc; Yp=G;  NX=1024; NY=8192; ls=3; lc=1; local=W;     mbase=0; }
    else if (W < 128)  { Xp=G;  Yp=Xc; NX=8192; NY=1024; ls=0; lc=4; local=W-64;  mbase=4096; }
    else if (W < 640)  { Xp=Xf; Yp=G;  NX=8192; NY=8192; ls=3; lc=4; local=W-128; mbase=36864; }
    else               { Xp=G;  Yp=Xf; NX=8192; NY=8192; ls=3; lc=4; local=W-640; mbase=69632; }
    const int split  = local & ((1 << ls) - 1);
    const int rest   = local >> ls;
    const int chunk4 = rest & ((1 << lc) - 1);
    const int b      = rest >> lc;

    // ---- stage 1024 Y as prebuilt A-frag dwords (4 Y per thread) ----
    // A k-seq: lanes<32 [yh0,yl0,yh0, yh1,yl1,yh1, yh2,yl2];
    //          lanes>=32 [yh2, wh, wl, 0...]  (w = |y|^2)   (verified r6-r8)
    const float* yg = Yp + ((size_t)b * NY + (size_t)split * 1024) * 3;
    #pragma unroll
    for (int it = 0; it < 4; ++it) {
        const int pt = tid + 256 * it;
        const float y0 = yg[pt*3+0], y1 = yg[pt*3+1], y2 = yg[pt*3+2];
        const float w  = fmaf(y0, y0, fmaf(y1, y1, y2 * y2));
        unsigned h0, L0, h1, L1, h2, L2, hw, Lw;
        split2(y0, h0, L0); split2(y1, h1, L1);
        split2(y2, h2, L2); split2(w,  hw, Lw);
        alo[pt] = make_uint4(h0 | (L0 << 16), h0 | (h1 << 16),
                             L1 | (h1 << 16), h2 | (L2 << 16));
        ahi[pt] = make_uint4(h2 | (hw << 16), Lw, 0u, 0u);
    }

    // ---- B-frags: 4 frags x 32 X points per wave (wave owns 128 X) ----
    // B k-seq (x scaled -2): lanes<32 [m2xh0,m2xh0,m2xl0, m2xh1,m2xh1,m2xl1,
    // m2xh2,m2xh2]; lanes>=32 [m2xl2, 1, 1, 0...]   (verified r6)
    const float* xg = Xp + ((size_t)b * NX + (size_t)chunk4 * 512 + (size_t)wv * 128) * 3;
    bf16x8 Bf[4]; float x2s[4];
    #pragma unroll
    for (int f = 0; f < 4; ++f) {
        const int p = f * 32 + l31;
        const float x0 = xg[p*3+0], x1 = xg[p*3+1], x2 = xg[p*3+2];
        x2s[f] = fmaf(x0, x0, fmaf(x1, x1, x2 * x2));
        unsigned sh0, sl0, sh1, sl1, sh2, sl2;
        split2(-2.f * x0, sh0, sl0);
        split2(-2.f * x1, sh1, sl1);
        split2(-2.f * x2, sh2, sl2);
        union { unsigned u[4]; bf16x8 v; } bu;
        bu.u[0] = hi ? (sl2 | (0x3F80u << 16)) : (sh0 | (sh0 << 16));
        bu.u[1] = hi ? 0x3F80u                 : (sl0 | (sh1 << 16));
        bu.u[2] = hi ? 0u                      : (sh1 | (sl1 << 16));
        bu.u[3] = hi ? 0u                      : (sh2 | (sh2 << 16));
        Bf[f] = bu.v;
    }

    float best[4][8];
    #pragma unroll
    for (int f = 0; f < 4; ++f)
        #pragma unroll
        for (int j = 0; j < 8; ++j) best[f][j] = 3.0e38f;

    const f32x16 zc = (f32x16)0.0f;
    const uint4* __restrict__ abase = hi ? ahi : alo;

    __syncthreads();

    // ---- 32 Y-tiles; MFMAs issued in pairs so folds overlap next MFMA ----
    #pragma unroll 2
    for (int t = 0; t < 32; ++t) {
        const uint4 dd = abase[t * 32 + l31];
        union { uint4 u; bf16x8 v; } au; au.u = dd;
        const bf16x8 Af = au.v;
        #pragma unroll
        for (int fp = 0; fp < 2; ++fp) {
            const int f0 = fp * 2, f1 = fp * 2 + 1;
            const f32x16 acc0 = __builtin_amdgcn_mfma_f32_32x32x16_bf16(Af, Bf[f0], zc, 0, 0, 0);
            const f32x16 acc1 = __builtin_amdgcn_mfma_f32_32x32x16_bf16(Af, Bf[f1], zc, 0, 0, 0);
            #pragma unroll
            for (int j = 0; j < 8; ++j)
                best[f0][j] = fminf(fminf(best[f0][j], acc0[2*j]), acc0[2*j+1]);
            #pragma unroll
            for (int j = 0; j < 8; ++j)
                best[f1][j] = fminf(fminf(best[f1][j], acc1[2*j]), acc1[2*j+1]);
        }
    }

    // ---- epilogue: fold 8 best, merge k-halves, d = |x|^2 + tmin >= 0 ----
    unsigned* mp = mins + mbase + b * NX + chunk4 * 512 + wv * 128;
    #pragma unroll
    for (int f = 0; f < 4; ++f) {
        const float m0 = fminf(fminf(best[f][0], best[f][1]), best[f][2]);
        const float m1 = fminf(fminf(best[f][3], best[f][4]), best[f][5]);
        const float m2 = fminf(fminf(best[f][6], best[f][7]), m0);
        float tm = fminf(m1, m2);
        tm = fminf(tm, __shfl_xor(tm, 32, 64));
        const float d = fmaxf(x2s[f] + tm, 0.0f);
        atomicMin(mp + f * 32 + l31, __float_as_uint(d));
    }
}

// ONE block, 1024 threads: read 400 KB of mins, weighted sum, plain store.
__global__ __launch_bounds__(1024) void pccl_sum(
    const unsigned* __restrict__ mins,
    const int* __restrict__ pc, const int* __restrict__ pf,
    float* __restrict__ out)
{
    const int tid = threadIdx.x;
    const int lane = tid & 63;
    const int wv = tid >> 6;
    float w0 = 0.f, w1 = 0.f;   // coarse-loss sum, fine-loss sum (unscaled)
    #pragma unroll 5
    for (int k = 0; k < 25; ++k) {
        const int q = tid + 1024 * k;
        const uint4 v = ((const uint4*)mins)[q];
        const float s = __uint_as_float(v.x) + __uint_as_float(v.y)
                      + __uint_as_float(v.z) + __uint_as_float(v.w);
        if (q < 1024)       w0 += s * (1.f / 4096.f);
        else if (q < 9216)  w0 += s * (1.f / 32768.f);
        else                w1 += s * (1.f / 32768.f);
    }
    #pragma unroll
    for (int off = 1; off < 64; off <<= 1) {
        w0 += __shfl_xor(w0, off, 64);
        w1 += __shfl_xor(w1, off, 64);
    }
    __shared__ float s0[16], s1[16];
    if (lane == 0) { s0[wv] = w0; s1[wv] = w1; }
    __syncthreads();
    if (tid == 0) {
        float a0 = 0.f, a1 = 0.f;
        #pragma unroll
        for (int i = 0; i < 16; ++i) { a0 += s0[i]; a1 += s1[i]; }
        out[0] = a0 * (float)pc[0];
        out[1] = a1 * (float)pf[0];
    }
}

extern "C" void kernel_launch(void* const* d_in, const int* in_sizes, int n_in,
                              void* d_out, int out_size, void* d_ws, size_t ws_size,
                              hipStream_t stream) {
    const float* coarse = (const float*)d_in[0];
    const float* fine   = (const float*)d_in[1];
    const float* gt     = (const float*)d_in[2];
    const int*   pc     = (const int*)d_in[3];
    const int*   pf     = (const int*)d_in[4];
    float* out = (float*)d_out;
    unsigned* mins = (unsigned*)d_ws;

    hipMemsetAsync(mins, 0x7F, (size_t)NMINS * 4, stream);  // 3.396e38 sentinel
    pccl_stage<<<NBLK, 256, 0, stream>>>(coarse, fine, gt, mins);
    pccl_sum<<<1, 1024, 0, stream>>>(mins, pc, pf, out);
}